// Round 6
// baseline (1090.970 us; speedup 1.0000x reference)
//
#include <hip/hip_runtime.h>

// ---------------------------------------------------------------------------
// PAM_Module_Dep: dual-modality position attention. B=4, C=512, N=4096, CQ=64.
// Round 6: same barrier-free flash structure as round 5, but 2 waves/SIMD:
//   - wave = 16 rows x 512 ch x j-half -> acc[32] = 128 AGPRs (was 256)
//   - block = 8 waves (ic x jh), 64 rows; grid 256 -> 16 waves/CU, 2/SIMD
//   - 132 KB red buffer -> 34 KB chunked jh-reduction (barriers only at end)
// Round-5 evidence: dur*MfmaUtil ~= 56 us const; 1 wave/SIMD exposed the
// serial K->MFMA->exp->LDS->V->MFMA chain. Second wave/SIMD fills the pipe.
// Verified math retained: two-pass flash (hi-only m-hat), split-bf16 exact
// energy (hh+hl+lh), p rounded to bf16 with l summed from rounded p,
// O^T = V^T * P^T, out = gamma*O/l + x. Dtype detection retained.
// ---------------------------------------------------------------------------

typedef __attribute__((ext_vector_type(8))) short bf16x8;
typedef __attribute__((ext_vector_type(4))) float f32x4;

__device__ __forceinline__ float bf2f(unsigned short u) {
  return __builtin_bit_cast(float, (unsigned int)u << 16);
}
__device__ __forceinline__ unsigned short f2bf(float f) {
  unsigned int u = __builtin_bit_cast(unsigned int, f);
  u = u + 0x7fffu + ((u >> 16) & 1u);   // RNE
  return (unsigned short)(u >> 16);
}
__device__ __forceinline__ float bflo(unsigned int u) {
  return __builtin_bit_cast(float, u << 16);
}

// Returns 1 if x looks like fp32 data, 0 if bf16. Wave-uniform, deterministic.
__device__ __forceinline__ int detect_fp32_mode(const void* xv) {
  const unsigned int* p = (const unsigned int*)xv;
  const int lane = threadIdx.x & 63;
  const unsigned int w0 = p[lane];
  const unsigned int w1 = p[64 + lane];
  int cnt = 0;
  const unsigned short us[4] = {
      (unsigned short)(w0 & 0xffffu), (unsigned short)(w0 >> 16),
      (unsigned short)(w1 & 0xffffu), (unsigned short)(w1 >> 16)};
#pragma unroll
  for (int h = 0; h < 4; ++h) {
    const float a = fabsf(bf2f(us[h]));
    cnt += (a > 9.0e-13f && a < 32.0f) ? 1 : 0;
  }
#pragma unroll
  for (int mm = 32; mm >= 1; mm >>= 1) cnt += __shfl_xor(cnt, mm, 64);
  return cnt < 220;
}

// ---------------------------------------------------------------------------
// prep: canonicalize weights into ws as split hi/lo bf16; biases+gamma fp32.
// ---------------------------------------------------------------------------
__global__ __launch_bounds__(256) void prep_kernel(
    const void* wq, const void* bq, const void* wqd, const void* bqd,
    const void* wk, const void* bk, const void* wkd, const void* bkd,
    const void* wv, const void* bv, const void* gam, const void* x,
    unsigned short* __restrict__ Whi, unsigned short* __restrict__ Wlo,
    float* __restrict__ Bcat, float* __restrict__ gamF)
{
  const int fp32mode = detect_fp32_mode(x);
  const int row = blockIdx.x;                    // 0..767
  const void* src; const void* bsrc; int srow;
  if (row < 64)       { src = wq;  bsrc = bq;  srow = row; }
  else if (row < 128) { src = wqd; bsrc = bqd; srow = row - 64; }
  else if (row < 192) { src = wk;  bsrc = bk;  srow = row - 128; }
  else if (row < 256) { src = wkd; bsrc = bkd; srow = row - 192; }
  else                { src = wv;  bsrc = bv;  srow = row - 256; }
  for (int c = threadIdx.x; c < 512; c += 256) {
    const float v = fp32mode ? ((const float*)src)[(size_t)srow * 512 + c]
                             : bf2f(((const unsigned short*)src)[(size_t)srow * 512 + c]);
    const unsigned short h = f2bf(v);
    Whi[(size_t)row * 512 + c] = h;
    Wlo[(size_t)row * 512 + c] = f2bf(v - bf2f(h));
  }
  if (threadIdx.x == 0) {
    Bcat[row] = fp32mode ? ((const float*)bsrc)[srow]
                         : bf2f(((const unsigned short*)bsrc)[srow]);
    if (row == 0)
      gamF[0] = fp32mode ? ((const float*)gam)[0]
                         : bf2f(((const unsigned short*)gam)[0]);
  }
}

// ---------------------------------------------------------------------------
// Projection tile, BOTH 16-col subtiles per W-fragment load.
// C/D: col=lane&15 (n), row=quad*4+reg.
// ---------------------------------------------------------------------------
__device__ __forceinline__ void do_tile2(
    const unsigned short* __restrict__ Whi, const unsigned short* __restrict__ Wlo,
    const float* bsh,
    const unsigned short* Xhi, const unsigned short* Xlo, int fp32mode,
    int wrow0, int kind, int d0,
    int b, int n0, int l15, int quad,
    unsigned short* __restrict__ Qhi, unsigned short* __restrict__ Qlo,
    unsigned short* __restrict__ Khi, unsigned short* __restrict__ Klo,
    unsigned short* __restrict__ V)
{
  f32x4 a0, a1;
#pragma unroll
  for (int r = 0; r < 4; ++r) a0[r] = a1[r] = bsh[wrow0 + quad * 4 + r];
  const unsigned short* whi = Whi + (size_t)(wrow0 + l15) * 512;
  const unsigned short* wlo = Wlo + (size_t)(wrow0 + l15) * 512;
  const unsigned short* x0h = Xhi + l15 * 520;
  const unsigned short* x1h = Xhi + (16 + l15) * 520;
  const unsigned short* x0l = Xlo + l15 * 520;
  const unsigned short* x1l = Xlo + (16 + l15) * 520;
#pragma unroll
  for (int ks = 0; ks < 16; ++ks) {
    const int o = ks * 32 + quad * 8;
    const bf16x8 ah = *(const bf16x8*)(whi + o);
    const bf16x8 b0 = *(const bf16x8*)(x0h + o);
    const bf16x8 b1 = *(const bf16x8*)(x1h + o);
    a0 = __builtin_amdgcn_mfma_f32_16x16x32_bf16(ah, b0, a0, 0, 0, 0);
    a1 = __builtin_amdgcn_mfma_f32_16x16x32_bf16(ah, b1, a1, 0, 0, 0);
    if (fp32mode) {
      const bf16x8 al_ = *(const bf16x8*)(wlo + o);
      const bf16x8 c0 = *(const bf16x8*)(x0l + o);
      const bf16x8 c1 = *(const bf16x8*)(x1l + o);
      a0 = __builtin_amdgcn_mfma_f32_16x16x32_bf16(ah, c0, a0, 0, 0, 0);
      a0 = __builtin_amdgcn_mfma_f32_16x16x32_bf16(al_, b0, a0, 0, 0, 0);
      a1 = __builtin_amdgcn_mfma_f32_16x16x32_bf16(ah, c1, a1, 0, 0, 0);
      a1 = __builtin_amdgcn_mfma_f32_16x16x32_bf16(al_, b1, a1, 0, 0, 0);
    }
  }
#pragma unroll
  for (int ns = 0; ns < 2; ++ns) {
    const f32x4 acc = ns ? a1 : a0;
    const int n = n0 + ns * 16 + l15;
    if (kind <= 1) {                     // Q or K: [b][n][128] hi/lo
      ushort4 h, l;
#pragma unroll
      for (int r = 0; r < 4; ++r) {
        const float f = acc[r];
        const unsigned short hh = f2bf(f);
        ((unsigned short*)&h)[r] = hh;
        ((unsigned short*)&l)[r] = f2bf(f - bf2f(hh));
      }
      const size_t base = (((size_t)b << 12) + n) * 128 + d0 + quad * 4;
      if (kind == 0) { *(ushort4*)(Qhi + base) = h; *(ushort4*)(Qlo + base) = l; }
      else           { *(ushort4*)(Khi + base) = h; *(ushort4*)(Klo + base) = l; }
    } else {                             // V: [b][c][4096]
#pragma unroll
      for (int r = 0; r < 4; ++r)
        V[(((size_t)b * 512 + d0 + quad * 4 + r) << 12) + n] = f2bf(acc[r]);
    }
  }
}

__global__ __launch_bounds__(512, 4) void proj_kernel(
    const void* __restrict__ x, const void* __restrict__ dep,
    const unsigned short* __restrict__ Whi, const unsigned short* __restrict__ Wlo,
    const float* __restrict__ Bcat,
    unsigned short* __restrict__ Qhi, unsigned short* __restrict__ Qlo,
    unsigned short* __restrict__ Khi, unsigned short* __restrict__ Klo,
    unsigned short* __restrict__ V)
{
  __shared__ unsigned short Xhi[32 * 520];   // 33.3 KB
  __shared__ unsigned short Xlo[32 * 520];
  __shared__ float bsh[768];
  const int fp32mode = detect_fp32_mode(x);
  const int tid  = threadIdx.x;
  const int lane = tid & 63;
  const int w    = tid >> 6;           // 0..7
  const int l15  = lane & 15;
  const int quad = lane >> 4;
  const int b  = blockIdx.y;
  const int n0 = blockIdx.x * 32;

  const int cbase = tid >> 4;          // 0..31
  const int nn    = (tid & 15) * 2;

  for (int i = tid; i < 768; i += 512) bsh[i] = Bcat[i];

  for (int r = 0; r < 16; ++r) {
    const int c = cbase + r * 32;
    const size_t off = (((size_t)b * 512 + c) << 12) + n0 + nn;
    float v0, v1;
    if (fp32mode) {
      const float2 f2 = *(const float2*)((const float*)x + off);
      v0 = f2.x; v1 = f2.y;
    } else {
      const unsigned int v2 = *(const unsigned int*)((const unsigned short*)x + off);
      v0 = bflo(v2 & 0xffffu); v1 = bflo(v2 >> 16);
    }
    const unsigned short h0 = f2bf(v0), h1 = f2bf(v1);
    Xhi[nn * 520 + c]       = h0;
    Xhi[(nn + 1) * 520 + c] = h1;
    Xlo[nn * 520 + c]       = f2bf(v0 - bf2f(h0));
    Xlo[(nn + 1) * 520 + c] = f2bf(v1 - bf2f(h1));
  }
  __syncthreads();

  // stage-1 (from x): 40 tiles = wq(4) | wk(4) | wv(32); wave stride 8
  for (int rt = w; rt < 40; rt += 8) {
    if (rt < 4)
      do_tile2(Whi, Wlo, bsh, Xhi, Xlo, fp32mode, rt * 16,             0, rt * 16,
               b, n0, l15, quad, Qhi, Qlo, Khi, Klo, V);
    else if (rt < 8)
      do_tile2(Whi, Wlo, bsh, Xhi, Xlo, fp32mode, 128 + (rt - 4) * 16, 1, (rt - 4) * 16,
               b, n0, l15, quad, Qhi, Qlo, Khi, Klo, V);
    else
      do_tile2(Whi, Wlo, bsh, Xhi, Xlo, fp32mode, 256 + (rt - 8) * 16, 2, (rt - 8) * 16,
               b, n0, l15, quad, Qhi, Qlo, Khi, Klo, V);
  }
  __syncthreads();

  for (int r = 0; r < 16; ++r) {
    const int c = cbase + r * 32;
    const size_t off = (((size_t)b * 512 + c) << 12) + n0 + nn;
    float v0, v1;
    if (fp32mode) {
      const float2 f2 = *(const float2*)((const float*)dep + off);
      v0 = f2.x; v1 = f2.y;
    } else {
      const unsigned int v2 = *(const unsigned int*)((const unsigned short*)dep + off);
      v0 = bflo(v2 & 0xffffu); v1 = bflo(v2 >> 16);
    }
    const unsigned short h0 = f2bf(v0), h1 = f2bf(v1);
    Xhi[nn * 520 + c]       = h0;
    Xhi[(nn + 1) * 520 + c] = h1;
    Xlo[nn * 520 + c]       = f2bf(v0 - bf2f(h0));
    Xlo[(nn + 1) * 520 + c] = f2bf(v1 - bf2f(h1));
  }
  __syncthreads();

  // stage-2 (from dep): wqd(4) | wkd(4), one tile per wave, d-base 64
  {
    const int rt = w;
    if (rt < 4)
      do_tile2(Whi, Wlo, bsh, Xhi, Xlo, fp32mode, 64 + rt * 16,        0, 64 + rt * 16,
               b, n0, l15, quad, Qhi, Qlo, Khi, Klo, V);
    else
      do_tile2(Whi, Wlo, bsh, Xhi, Xlo, fp32mode, 192 + (rt - 4) * 16, 1, 64 + (rt - 4) * 16,
               b, n0, l15, quad, Qhi, Qlo, Khi, Klo, V);
  }
}

// ---------------------------------------------------------------------------
// Barrier-free MFMA flash attention, 2 waves/SIMD.
// Grid: 256 blocks x 512 thr (8 waves). Block covers 64 rows of one batch.
//   wave w: ic = w&3 (16-row chunk), jh = w>>2 (j-half).
// Wave: E^T = K*Q^T (split exact) -> exp -> wave-private LDS transpose ->
//       O^T += V^T * P^T over all 512 channels. acc[32] = 128 AGPRs.
// Barriers: 1 (pass-1 max combine) + chunked jh-reduction at END only.
// ---------------------------------------------------------------------------
__global__ __launch_bounds__(512, 2) void attn_kernel(
    const unsigned short* __restrict__ Qhi, const unsigned short* __restrict__ Qlo,
    const unsigned short* __restrict__ Khi, const unsigned short* __restrict__ Klo,
    const unsigned short* __restrict__ V,
    const void* __restrict__ x, const float* __restrict__ gamF,
    void* __restrict__ outp)
{
  __shared__ float red[64][132];                  // 33.8 KB chunked jh-reduce
  __shared__ unsigned short pscr[8][16 * 40];     // 10.2 KB wave-private P^T
  __shared__ float mstat[2][4][16];
  __shared__ float lstat[2][4][16];

  const int fp32mode = detect_fp32_mode(x);
  const int tid  = threadIdx.x;
  const int lane = tid & 63;
  const int w    = tid >> 6;          // 0..7
  const int l15  = lane & 15;
  const int quad = lane >> 4;
  const int ic   = w & 3;             // 16-row chunk
  const int jh   = w >> 2;            // j-half
  const int id   = blockIdx.x;
  const int b    = (id >> 1) & 3;
  const int n0   = (((id >> 3) << 1) | (id & 1)) * 64;

  // Q fragments (16 rows), hi+lo
  bf16x8 qh[4], ql[4];
  {
    const size_t qb = (((size_t)b << 12) + n0 + ic * 16 + l15) * 128 + quad * 8;
#pragma unroll
    for (int ds = 0; ds < 4; ++ds) {
      qh[ds] = *(const bf16x8*)(Qhi + qb + ds * 32);
      ql[ds] = *(const bf16x8*)(Qlo + qb + ds * 32);
    }
  }

  // ---- pass 1: row maxima over this j-half, hi-only E^T ----
  float rm = -3.0e38f;
  {
    const size_t kb0 = (((size_t)b << 12) + jh * 2048 + l15) * 128 + quad * 8;
    for (int t = 0; t < 128; t += 2) {
      const unsigned short* ka = Khi + kb0 + (size_t)t * 2048;
      f32x4 e0 = {0.f, 0.f, 0.f, 0.f}, e1 = {0.f, 0.f, 0.f, 0.f};
#pragma unroll
      for (int ds = 0; ds < 4; ++ds) {
        const bf16x8 kfa = *(const bf16x8*)(ka + ds * 32);
        const bf16x8 kfb = *(const bf16x8*)(ka + 2048 + ds * 32);
        e0 = __builtin_amdgcn_mfma_f32_16x16x32_bf16(kfa, qh[ds], e0, 0, 0, 0);
        e1 = __builtin_amdgcn_mfma_f32_16x16x32_bf16(kfb, qh[ds], e1, 0, 0, 0);
      }
#pragma unroll
      for (int r = 0; r < 4; ++r) rm = fmaxf(rm, fmaxf(e0[r], e1[r]));
    }
  }
  rm = fmaxf(rm, __shfl_xor(rm, 16, 64));
  rm = fmaxf(rm, __shfl_xor(rm, 32, 64));
  if (quad == 0) mstat[jh][ic][l15] = rm;
  __syncthreads();
  const float mh = fmaxf(mstat[0][ic][l15], mstat[1][ic][l15]);

  // ---- pass 2: barrier-free main loop ----
  f32x4 acc[32];
#pragma unroll
  for (int ct = 0; ct < 32; ++ct) acc[ct] = (f32x4){0.f, 0.f, 0.f, 0.f};
  float lpart = 0.f;

  unsigned short* myscr = &pscr[w][0];            // [i=l15][40 j-shorts]
  const unsigned short* vbase =
      V + (((size_t)b * 512 + l15) << 12) + quad * 8;

  for (int itr = 0; itr < 64; ++itr) {
    const int j0 = jh * 2048 + itr * 32;
    // K fragments for two 16-j tiles (issued first, consumed by energy)
    const size_t kb = (((size_t)b << 12) + j0 + l15) * 128 + quad * 8;
    bf16x8 kh[2][4], kl[2][4];
#pragma unroll
    for (int t = 0; t < 2; ++t)
#pragma unroll
      for (int ds = 0; ds < 4; ++ds) {
        kh[t][ds] = *(const bf16x8*)(Khi + kb + t * 2048 + ds * 32);
        kl[t][ds] = *(const bf16x8*)(Klo + kb + t * 2048 + ds * 32);
      }
    // split-exact E^T = K*Q^T (hh + hl + lh)
    f32x4 e[2];
    e[0] = (f32x4){0.f, 0.f, 0.f, 0.f};
    e[1] = (f32x4){0.f, 0.f, 0.f, 0.f};
#pragma unroll
    for (int ds = 0; ds < 4; ++ds)
#pragma unroll
      for (int t = 0; t < 2; ++t)
        e[t] = __builtin_amdgcn_mfma_f32_16x16x32_bf16(kh[t][ds], qh[ds], e[t], 0, 0, 0);
#pragma unroll
    for (int ds = 0; ds < 4; ++ds)
#pragma unroll
      for (int t = 0; t < 2; ++t) {
        e[t] = __builtin_amdgcn_mfma_f32_16x16x32_bf16(kh[t][ds], ql[ds], e[t], 0, 0, 0);
        e[t] = __builtin_amdgcn_mfma_f32_16x16x32_bf16(kl[t][ds], qh[ds], e[t], 0, 0, 0);
      }
    // exp -> bf16 p -> wave-private scratch [i][j_local] (stride 40 shorts)
#pragma unroll
    for (int t = 0; t < 2; ++t) {
      const float p0 = __expf(e[t][0] - mh);
      const float p1 = __expf(e[t][1] - mh);
      const float p2 = __expf(e[t][2] - mh);
      const float p3 = __expf(e[t][3] - mh);
      const unsigned short u0 = f2bf(p0), u1 = f2bf(p1);
      const unsigned short u2 = f2bf(p2), u3 = f2bf(p3);
      lpart += (bf2f(u0) + bf2f(u1)) + (bf2f(u2) + bf2f(u3));
      unsigned int* dst = (unsigned int*)(myscr + l15 * 40 + t * 16 + quad * 4);
      dst[0] = (unsigned int)u0 | ((unsigned int)u1 << 16);
      dst[1] = (unsigned int)u2 | ((unsigned int)u3 << 16);
    }
    // read P^T B-frag: lane(quad,l15): k=j_local=quad*8+jj, n=i=l15
    const bf16x8 pf = *(const bf16x8*)(myscr + l15 * 40 + quad * 8);
    // PV: O^T[c][i] += V^T[c][j] * P^T[j][i] over all 512 channels
    const unsigned short* vp = vbase + j0;
#pragma unroll
    for (int ct = 0; ct < 32; ++ct) {
      const bf16x8 va = *(const bf16x8*)(vp + ((size_t)ct << 16));
      acc[ct] = __builtin_amdgcn_mfma_f32_16x16x32_bf16(va, pf, acc[ct], 0, 0, 0);
    }
  }

  // ---- l reduction ----
  {
    float lp = lpart;
    lp += __shfl_xor(lp, 16, 64);
    lp += __shfl_xor(lp, 32, 64);
    if (quad == 0) lstat[jh][ic][l15] = lp;
  }

  // ---- chunked jh pair-reduction (4 chunks of 128 channels) ----
#pragma unroll
  for (int cc = 0; cc < 4; ++cc) {
    if (jh == 1) {
#pragma unroll
      for (int t8 = 0; t8 < 8; ++t8)
        *(f32x4*)&red[ic * 16 + l15][t8 * 16 + quad * 4] = acc[cc * 8 + t8];
    }
    __syncthreads();
    if (jh == 0) {
#pragma unroll
      for (int t8 = 0; t8 < 8; ++t8) {
        const f32x4 o = *(const f32x4*)&red[ic * 16 + l15][t8 * 16 + quad * 4];
        acc[cc * 8 + t8] += o;
      }
    }
    __syncthreads();
  }
  if (jh == 1) return;

  // ---- epilogue (jh==0 waves): out[c][n] = gamma*O/l + x ----
  const float gv = gamF[0];
  const float sc = gv / (lstat[0][ic][l15] + lstat[1][ic][l15]);
#pragma unroll
  for (int ct = 0; ct < 32; ++ct)
#pragma unroll
    for (int r = 0; r < 4; ++r) {
      const int c_g = ct * 16 + quad * 4 + r;
      const size_t addr = (((size_t)b * 512 + c_g) << 12) + n0 + ic * 16 + l15;
      const float o = sc * acc[ct][r];
      if (fp32mode) {
        ((float*)outp)[addr] = o + ((const float*)x)[addr];
      } else {
        ((unsigned short*)outp)[addr] =
            f2bf(o + bf2f(((const unsigned short*)x)[addr]));
      }
    }
}

extern "C" void kernel_launch(void* const* d_in, const int* in_sizes, int n_in,
                              void* d_out, int out_size, void* d_ws, size_t ws_size,
                              hipStream_t stream) {
  const void* x    = d_in[0];
  const void* dep  = d_in[1];
  const void* wq   = d_in[2];
  const void* bq   = d_in[3];
  const void* wqd  = d_in[4];
  const void* bqd  = d_in[5];
  const void* wk   = d_in[6];
  const void* bk   = d_in[7];
  const void* wkd  = d_in[8];
  const void* bkd  = d_in[9];
  const void* wv   = d_in[10];
  const void* bv   = d_in[11];
  const void* gam  = d_in[12];

  // ws: Whi(768K) Wlo(768K) Bcat gamF | @2M Qhi 4M | @6M Qlo 4M | @10M Khi 4M
  //     | @14M Klo 4M | @18M V 16M  (34 MB total)
  unsigned short* Whi = (unsigned short*)d_ws;
  unsigned short* Wlo = Whi + (size_t)768 * 512;
  float* Bcat = (float*)(Wlo + (size_t)768 * 512);
  float* gamF = Bcat + 768;
  unsigned short* Qhi = (unsigned short*)((char*)d_ws + ((size_t)2 << 20));
  unsigned short* Qlo = (unsigned short*)((char*)d_ws + ((size_t)6 << 20));
  unsigned short* Khi = (unsigned short*)((char*)d_ws + ((size_t)10 << 20));
  unsigned short* Klo = (unsigned short*)((char*)d_ws + ((size_t)14 << 20));
  unsigned short* V   = (unsigned short*)((char*)d_ws + ((size_t)18 << 20));

  prep_kernel<<<768, 256, 0, stream>>>(wq, bq, wqd, bqd, wk, bk, wkd, bkd,
                                       wv, bv, gam, x, Whi, Wlo, Bcat, gamF);
  proj_kernel<<<dim3(128, 4), 512, 0, stream>>>(x, dep, Whi, Wlo, Bcat,
                                                Qhi, Qlo, Khi, Klo, V);
  attn_kernel<<<256, 512, 0, stream>>>(Qhi, Qlo, Khi, Klo, V, x, gamF, d_out);
}